// Round 6
// baseline (113.936 us; speedup 1.0000x reference)
//
#include <hip/hip_runtime.h>

// SSIM loss, wave-autonomous + register ring buffer. B=32, H=W=512, win=11.
// Each wave: 128-col strip (118 outputs, 2 cols/lane) x 44-row band.
// Vertical moment sums in registers; trailing 11 rows ring-buffered in VGPRs.
// Horizontal 11-tap via pair DPP-scan + shfl. 4-row-deep load prefetch
// (outstanding-bytes limited at depth 1: ~2.9 TB/s achieved; depth 4 -> ~4x
// bytes in flight per wave at zero extra fetch).
// 1920 waves = 480 blocks x 256 thr. atomicAdd into d_out.

#define WW 512
#define OH 502
#define BANDR 44
#define NBANDS 12
#define INV_N (1.0f / 8064128.0f)   // 32*502*502

#define DPP_ADD(x, ctrl, rmask)                                            \
    x += __int_as_float(__builtin_amdgcn_update_dpp(                       \
        0, __float_as_int(x), (ctrl), (rmask), 0xf, true))

__device__ __forceinline__ float wave_iscan(float x) {
    DPP_ADD(x, 0x111, 0xf);   // row_shr:1
    DPP_ADD(x, 0x112, 0xf);   // row_shr:2
    DPP_ADD(x, 0x114, 0xf);   // row_shr:4
    DPP_ADD(x, 0x118, 0xf);   // row_shr:8
    DPP_ADD(x, 0x142, 0xa);   // row_bcast:15 -> rows 1,3
    DPP_ADD(x, 0x143, 0xc);   // row_bcast:31 -> rows 2,3
    return x;
}

// 11-tap horizontal window sums for this lane's two columns (2l, 2l+1).
__device__ __forceinline__ float2 hwin(float v0, float v1, int lane) {
    float e = v0 + v1;            // pair sum
    float S = wave_iscan(e);      // inclusive scan over pairs
    float A4 = __shfl(S, lane + 4);
    float A5 = __shfl(S, lane + 5);
    float v5 = __shfl(v0, lane + 5);
    float W0 = A4 - S + e + v5;   // pairs l..l+4  + col 2l+10
    float W1 = A5 - S + v1;       // pairs l+1..l+5 + col 2l+1
    return make_float2(W0, W1);
}

__device__ __forceinline__ float ssim_term(float s0, float s1, float sq, float sx) {
    const float NP  = 121.f;
    const float cn  = 121.f / 120.f;
    const float C1n = 1e-4f * 121.f * 121.f;
    const float C2n = 9e-4f * 121.f * 121.f;
    float m1 = s0 * s1;
    float q1 = fmaf(s0, s0, s1 * s1);
    float A1 = fmaf(2.f, m1, C1n);
    float B1 = q1 + C1n;
    float A2 = fmaf(2.f * cn, fmaf(NP, sx, -m1), C2n);
    float B2 = fmaf(cn, fmaf(NP, sq, -q1), C2n);
    return A1 * A2 * __builtin_amdgcn_rcpf(B1 * B2);
}

__global__ __launch_bounds__(256)
void ssim_main(const float* __restrict__ Pg, const float* __restrict__ Tg,
               float* __restrict__ outp) {
    const int tid  = threadIdx.x;
    const int lane = tid & 63;
    const int wv   = tid >> 6;
    const int Wid  = blockIdx.x * 4 + wv;      // 0..1919
    const int img   = Wid / 60;                // 5 strips * 12 bands
    const int rem   = Wid - img * 60;
    const int strip = rem / NBANDS;
    const int band  = rem - strip * NBANDS;

    const int col0 = (strip == 4) ? 472 : strip * 118;
    const int outw = (strip == 4) ? 30 : 118;
    const int y0   = band * BANDR;
    const int rows = min(BANDR, OH - y0);      // band 11: 18

    const int cload = min(col0 + 2 * lane, 510);
    const bool ok   = lane < (outw >> 1);

    const float* Pb = Pg + img * (WW * WW);
    const float* Tb = Tg + img * (WW * WW);

    float2 prr[11], trr[11];
    float sp0 = 0.f, sp1 = 0.f, st0 = 0.f, st1 = 0.f;
    float sq0 = 0.f, sq1 = 0.f, sx0 = 0.f, sx1 = 0.f;

    // ---- prime: input rows y0..y0+9 into ring slots 0..9 ----
    #pragma unroll
    for (int r = 0; r < 10; ++r) {
        float2 p = *(const float2*)(Pb + (y0 + r) * WW + cload);
        float2 t = *(const float2*)(Tb + (y0 + r) * WW + cload);
        prr[r] = p; trr[r] = t;
        sp0 += p.x; sp1 += p.y; st0 += t.x; st1 += t.y;
        sq0 = fmaf(p.x, p.x, sq0); sq0 = fmaf(t.x, t.x, sq0);
        sq1 = fmaf(p.y, p.y, sq1); sq1 = fmaf(t.y, t.y, sq1);
        sx0 = fmaf(p.x, t.x, sx0); sx1 = fmaf(p.y, t.y, sx1);
    }
    // 4-deep prefetch pipeline: rows y0+10 .. y0+13
    float2 Pn0 = *(const float2*)(Pb + (y0 + 10) * WW + cload);
    float2 Tn0 = *(const float2*)(Tb + (y0 + 10) * WW + cload);
    float2 Pn1 = *(const float2*)(Pb + (y0 + 11) * WW + cload);
    float2 Tn1 = *(const float2*)(Tb + (y0 + 11) * WW + cload);
    float2 Pn2 = *(const float2*)(Pb + min(y0 + 12, 511) * WW + cload);
    float2 Tn2 = *(const float2*)(Tb + min(y0 + 12, 511) * WW + cload);
    float2 Pn3 = *(const float2*)(Pb + min(y0 + 13, 511) * WW + cload);
    float2 Tn3 = *(const float2*)(Tb + min(y0 + 13, 511) * WW + cload);

    float acc = 0.f;

    for (int yy = 0; yy < rows; yy += 11) {
        #pragma unroll
        for (int j = 0; j < 11; ++j) {
            if (yy + j < rows) {               // wave-uniform guard
                const int sn = (10 + j) % 11;  // static after unroll
                // consume prefetched row (depth 0)
                float2 Pc = Pn0, Tc = Tn0;
                prr[sn] = Pc; trr[sn] = Tc;
                sp0 += Pc.x; sp1 += Pc.y; st0 += Tc.x; st1 += Tc.y;
                sq0 = fmaf(Pc.x, Pc.x, sq0); sq0 = fmaf(Tc.x, Tc.x, sq0);
                sq1 = fmaf(Pc.y, Pc.y, sq1); sq1 = fmaf(Tc.y, Tc.y, sq1);
                sx0 = fmaf(Pc.x, Tc.x, sx0); sx1 = fmaf(Pc.y, Tc.y, sx1);
                // rotate pipeline, issue load 4 rows ahead
                Pn0 = Pn1; Tn0 = Tn1;
                Pn1 = Pn2; Tn1 = Tn2;
                Pn2 = Pn3; Tn2 = Tn3;
                int nr = min(y0 + 14 + yy + j, 511);
                Pn3 = *(const float2*)(Pb + nr * WW + cload);
                Tn3 = *(const float2*)(Tb + nr * WW + cload);
                // horizontal windows + SSIM
                float2 w0 = hwin(sp0, sp1, lane);
                float2 w1 = hwin(st0, st1, lane);
                float2 w2 = hwin(sq0, sq1, lane);
                float2 w3 = hwin(sx0, sx1, lane);
                if (ok) {
                    acc += ssim_term(w0.x, w1.x, w2.x, w3.x);
                    acc += ssim_term(w0.y, w1.y, w2.y, w3.y);
                }
                // subtract oldest row (ring slot j)
                float2 po = prr[j], to = trr[j];
                sp0 -= po.x; sp1 -= po.y; st0 -= to.x; st1 -= to.y;
                sq0 = fmaf(po.x, -po.x, sq0); sq0 = fmaf(to.x, -to.x, sq0);
                sq1 = fmaf(po.y, -po.y, sq1); sq1 = fmaf(to.y, -to.y, sq1);
                sx0 = fmaf(po.x, -to.x, sx0); sx1 = fmaf(po.y, -to.y, sx1);
            }
        }
    }

    // ---- reduce: wave -> block -> one atomicAdd ----
    #pragma unroll
    for (int off = 32; off > 0; off >>= 1) acc += __shfl_down(acc, off);
    __shared__ float wred[4];
    if (lane == 0) wred[wv] = acc;
    __syncthreads();
    if (tid == 0) {
        float s = wred[0] + wred[1] + wred[2] + wred[3];
        float contrib = -s * INV_N;
        if (blockIdx.x == 0) contrib += 1.0f;
        atomicAdd(outp, contrib);
    }
}

extern "C" void kernel_launch(void* const* d_in, const int* in_sizes, int n_in,
                              void* d_out, int out_size, void* d_ws, size_t ws_size,
                              hipStream_t stream) {
    const float* pred = (const float*)d_in[0];
    const float* targ = (const float*)d_in[1];
    float* out = (float*)d_out;

    hipMemsetAsync(out, 0, sizeof(float), stream);
    ssim_main<<<dim3(480), dim3(256), 0, stream>>>(pred, targ, out);
}

// Round 7
// 110.319 us; speedup vs baseline: 1.0328x; 1.0328x over previous
//
#include <hip/hip_runtime.h>

// SSIM loss, wave-autonomous + register ring buffer, ROW-PAIR ILP.
// B=32, H=W=512, win=11. Each wave: 128-col strip (118 out, 2 cols/lane)
// x 44-row band. Per iteration TWO output rows: S_a = S + ya;
// S_b = S_a - (ya-10) + yb -> 8 independent scan/bpermute chains fill the
// latency that made the 1-row/iter version stall ~2400 cyc/row.
// Ring slot of row r is (r - y0) % 11; with 22-row unroll blocks all slot
// indices are compile-time static. 1920 waves = 480 blocks x 256 thr.

#define WW 512
#define OH 502
#define BANDR 44
#define NBANDS 12
#define INV_N (1.0f / 8064128.0f)   // 32*502*502

#define DPP_ADD(x, ctrl, rmask)                                            \
    x += __int_as_float(__builtin_amdgcn_update_dpp(                       \
        0, __float_as_int(x), (ctrl), (rmask), 0xf, true))

__device__ __forceinline__ float wave_iscan(float x) {
    DPP_ADD(x, 0x111, 0xf);   // row_shr:1
    DPP_ADD(x, 0x112, 0xf);   // row_shr:2
    DPP_ADD(x, 0x114, 0xf);   // row_shr:4
    DPP_ADD(x, 0x118, 0xf);   // row_shr:8
    DPP_ADD(x, 0x142, 0xa);   // row_bcast:15 -> rows 1,3
    DPP_ADD(x, 0x143, 0xc);   // row_bcast:31 -> rows 2,3
    return x;
}

// 11-tap horizontal window sums for this lane's two columns (2l, 2l+1).
__device__ __forceinline__ float2 hwin(float v0, float v1, int lane) {
    float e = v0 + v1;            // pair sum
    float S = wave_iscan(e);      // inclusive scan over pairs
    float A4 = __shfl(S, lane + 4);
    float A5 = __shfl(S, lane + 5);
    float v5 = __shfl(v0, lane + 5);
    float W0 = A4 - S + e + v5;   // pairs l..l+4  + col 2l+10
    float W1 = A5 - S + v1;       // pairs l+1..l+5 + col 2l+1
    return make_float2(W0, W1);
}

__device__ __forceinline__ float ssim_term(float s0, float s1, float sq, float sx) {
    const float NP  = 121.f;
    const float cn  = 121.f / 120.f;
    const float C1n = 1e-4f * 121.f * 121.f;
    const float C2n = 9e-4f * 121.f * 121.f;
    float m1 = s0 * s1;
    float q1 = fmaf(s0, s0, s1 * s1);
    float A1 = fmaf(2.f, m1, C1n);
    float B1 = q1 + C1n;
    float A2 = fmaf(2.f * cn, fmaf(NP, sx, -m1), C2n);
    float B2 = fmaf(cn, fmaf(NP, sq, -q1), C2n);
    return A1 * A2 * __builtin_amdgcn_rcpf(B1 * B2);
}

__global__ __launch_bounds__(256, 1)
void ssim_main(const float* __restrict__ Pg, const float* __restrict__ Tg,
               float* __restrict__ outp) {
    const int tid  = threadIdx.x;
    const int lane = tid & 63;
    const int wv   = tid >> 6;
    const int Wid  = blockIdx.x * 4 + wv;      // 0..1919
    const int img   = Wid / 60;                // 5 strips * 12 bands
    const int rem   = Wid - img * 60;
    const int strip = rem / NBANDS;
    const int band  = rem - strip * NBANDS;

    const int col0 = (strip == 4) ? 472 : strip * 118;
    const int outw = (strip == 4) ? 30 : 118;
    const int y0   = band * BANDR;
    const int rows = min(BANDR, OH - y0);      // band 11: 18 (always even)

    const int cload = min(col0 + 2 * lane, 510);
    const bool ok   = lane < (outw >> 1);

    const float* Pb = Pg + img * (WW * WW);
    const float* Tb = Tg + img * (WW * WW);

    float2 prr[11], trr[11];
    float sp0 = 0.f, sp1 = 0.f, st0 = 0.f, st1 = 0.f;
    float sq0 = 0.f, sq1 = 0.f, sx0 = 0.f, sx1 = 0.f;

    // ---- prime: input rows y0..y0+9 into ring slots 0..9 ----
    #pragma unroll
    for (int r = 0; r < 10; ++r) {
        float2 p = *(const float2*)(Pb + (y0 + r) * WW + cload);
        float2 t = *(const float2*)(Tb + (y0 + r) * WW + cload);
        prr[r] = p; trr[r] = t;
        sp0 += p.x; sp1 += p.y; st0 += t.x; st1 += t.y;
        sq0 = fmaf(p.x, p.x, sq0); sq0 = fmaf(t.x, t.x, sq0);
        sq1 = fmaf(p.y, p.y, sq1); sq1 = fmaf(t.y, t.y, sq1);
        sx0 = fmaf(p.x, t.x, sx0); sx1 = fmaf(p.y, t.y, sx1);
    }
    // 2-pair prefetch pipeline: stage0 = rows y0+10/11, stage1 = y0+12/13
    float2 PA0 = *(const float2*)(Pb + (y0 + 10) * WW + cload);
    float2 TA0 = *(const float2*)(Tb + (y0 + 10) * WW + cload);
    float2 PB0 = *(const float2*)(Pb + (y0 + 11) * WW + cload);
    float2 TB0 = *(const float2*)(Tb + (y0 + 11) * WW + cload);
    float2 PA1 = *(const float2*)(Pb + min(y0 + 12, 511) * WW + cload);
    float2 TA1 = *(const float2*)(Tb + min(y0 + 12, 511) * WW + cload);
    float2 PB1 = *(const float2*)(Pb + min(y0 + 13, 511) * WW + cload);
    float2 TB1 = *(const float2*)(Tb + min(y0 + 13, 511) * WW + cload);

    float acc = 0.f;

    for (int blk = 0; blk < 2; ++blk) {
        #pragma unroll
        for (int p = 0; p < 11; ++p) {
            if (22 * blk + 2 * p < rows) {          // wave-uniform guard
                const int sa = (10 + 2 * p) % 11;   // slot for row ya
                const int sb = (2 * p) % 11;        // slot: sub (ya-10), then yb
                const int sc = (2 * p + 1) % 11;    // slot: sub (yb-10)
                // consume stage0 (rows ya = y0+10+2P, yb = ya+1)
                float2 Pa = PA0, Ta = TA0, Pc = PB0, Tc = TB0;
                // rotate stages, issue loads 2 pairs ahead
                PA0 = PA1; TA0 = TA1; PB0 = PB1; TB0 = TB1;
                int nb = y0 + 14 + 22 * blk + 2 * p;
                int r1 = min(nb, 511), r2 = min(nb + 1, 511);
                PA1 = *(const float2*)(Pb + r1 * WW + cload);
                TA1 = *(const float2*)(Tb + r1 * WW + cload);
                PB1 = *(const float2*)(Pb + r2 * WW + cload);
                TB1 = *(const float2*)(Tb + r2 * WW + cload);

                // ---- row a: S_a = S + ya ----
                prr[sa] = Pa; trr[sa] = Ta;
                float a_sp0 = sp0 + Pa.x, a_sp1 = sp1 + Pa.y;
                float a_st0 = st0 + Ta.x, a_st1 = st1 + Ta.y;
                float a_sq0 = fmaf(Pa.x, Pa.x, fmaf(Ta.x, Ta.x, sq0));
                float a_sq1 = fmaf(Pa.y, Pa.y, fmaf(Ta.y, Ta.y, sq1));
                float a_sx0 = fmaf(Pa.x, Ta.x, sx0);
                float a_sx1 = fmaf(Pa.y, Ta.y, sx1);
                float2 wa0 = hwin(a_sp0, a_sp1, lane);
                float2 wa1 = hwin(a_st0, a_st1, lane);
                float2 wa2 = hwin(a_sq0, a_sq1, lane);
                float2 wa3 = hwin(a_sx0, a_sx1, lane);

                // ---- row b: S_b = S_a - (ya-10) + yb ----
                float2 po = prr[sb], to = trr[sb];
                prr[sb] = Pc; trr[sb] = Tc;
                float b_sp0 = a_sp0 - po.x + Pc.x, b_sp1 = a_sp1 - po.y + Pc.y;
                float b_st0 = a_st0 - to.x + Tc.x, b_st1 = a_st1 - to.y + Tc.y;
                float b_sq0 = fmaf(Pc.x, Pc.x, fmaf(Tc.x, Tc.x,
                              fmaf(po.x, -po.x, fmaf(to.x, -to.x, a_sq0))));
                float b_sq1 = fmaf(Pc.y, Pc.y, fmaf(Tc.y, Tc.y,
                              fmaf(po.y, -po.y, fmaf(to.y, -to.y, a_sq1))));
                float b_sx0 = fmaf(Pc.x, Tc.x, fmaf(po.x, -to.x, a_sx0));
                float b_sx1 = fmaf(Pc.y, Tc.y, fmaf(po.y, -to.y, a_sx1));
                float2 wb0 = hwin(b_sp0, b_sp1, lane);
                float2 wb1 = hwin(b_st0, b_st1, lane);
                float2 wb2 = hwin(b_sq0, b_sq1, lane);
                float2 wb3 = hwin(b_sx0, b_sx1, lane);

                if (ok) {
                    acc += ssim_term(wa0.x, wa1.x, wa2.x, wa3.x);
                    acc += ssim_term(wa0.y, wa1.y, wa2.y, wa3.y);
                    acc += ssim_term(wb0.x, wb1.x, wb2.x, wb3.x);
                    acc += ssim_term(wb0.y, wb1.y, wb2.y, wb3.y);
                }

                // ---- S(next) = S_b - (yb-10) ----
                float2 po2 = prr[sc], to2 = trr[sc];
                sp0 = b_sp0 - po2.x; sp1 = b_sp1 - po2.y;
                st0 = b_st0 - to2.x; st1 = b_st1 - to2.y;
                sq0 = fmaf(po2.x, -po2.x, fmaf(to2.x, -to2.x, b_sq0));
                sq1 = fmaf(po2.y, -po2.y, fmaf(to2.y, -to2.y, b_sq1));
                sx0 = fmaf(po2.x, -to2.x, b_sx0);
                sx1 = fmaf(po2.y, -to2.y, b_sx1);
            }
        }
    }

    // ---- reduce: wave -> block -> one atomicAdd ----
    #pragma unroll
    for (int off = 32; off > 0; off >>= 1) acc += __shfl_down(acc, off);
    __shared__ float wred[4];
    if (lane == 0) wred[wv] = acc;
    __syncthreads();
    if (tid == 0) {
        float s = wred[0] + wred[1] + wred[2] + wred[3];
        float contrib = -s * INV_N;
        if (blockIdx.x == 0) contrib += 1.0f;
        atomicAdd(outp, contrib);
    }
}

extern "C" void kernel_launch(void* const* d_in, const int* in_sizes, int n_in,
                              void* d_out, int out_size, void* d_ws, size_t ws_size,
                              hipStream_t stream) {
    const float* pred = (const float*)d_in[0];
    const float* targ = (const float*)d_in[1];
    float* out = (float*)d_out;

    hipMemsetAsync(out, 0, sizeof(float), stream);
    ssim_main<<<dim3(480), dim3(256), 0, stream>>>(pred, targ, out);
}

// Round 8
// 108.704 us; speedup vs baseline: 1.0481x; 1.0149x over previous
//
#include <hip/hip_runtime.h>

// SSIM loss, wave-autonomous + register ring buffer. B=32, H=W=512, win=11.
// Each wave: 128-col strip (118 outputs, 2 cols/lane) x 44-row band.
// Vertical moment sums in registers; trailing 11 rows ring-buffered in VGPRs.
// Horizontal 11-tap via DPP-ONLY wave_shl:1 chains -- no ds_bpermute, no
// lgkmcnt waits in the hot loop (the round-4..7 stall source).
// 1920 waves = 480 blocks x 256 thr. atomicAdd into d_out.

#define WW 512
#define OH 502
#define BANDR 44
#define NBANDS 12
#define INV_N (1.0f / 8064128.0f)   // 32*502*502

// lane l receives lane l+1's value; lane 63 -> 0 (bound_ctrl).
// Direction check: our verified inclusive scan used row_shr (lane l reads
// l-1), so wave_shl (0x130) reads l+1.
__device__ __forceinline__ float shl1(float x) {
    return __int_as_float(__builtin_amdgcn_update_dpp(
        0, __float_as_int(x), 0x130, 0xf, 0xf, true));
}

// 11-tap horizontal window sums for this lane's two columns (2l, 2l+1).
// v0 = col 2l sum, v1 = col 2l+1 sum.
// A5 = pairs l..l+5 = cols 2l..2l+11 (12 taps);
// W0 = A5 - col 2l+11 = cols 2l..2l+10; W1 = A5 - col 2l = cols 2l+1..2l+11.
__device__ __forceinline__ float2 hwin(float v0, float v1) {
    float e = v0 + v1;
    float t = shl1(e);  float A = e + t;
    t = shl1(t);  A += t;
    t = shl1(t);  A += t;
    t = shl1(t);  A += t;
    t = shl1(t);  A += t;         // A = pairs l..l+5? no: e + t1..t5 = 6 pair terms
    float u = shl1(v1);
    u = shl1(u); u = shl1(u); u = shl1(u); u = shl1(u);  // v1[l+5] = col 2l+11
    float W0 = A - u;             // cols 2l .. 2l+10
    float W1 = A - v0;            // cols 2l+1 .. 2l+11
    return make_float2(W0, W1);
}

__device__ __forceinline__ float ssim_term(float s0, float s1, float sq, float sx) {
    const float NP  = 121.f;
    const float cn  = 121.f / 120.f;
    const float C1n = 1e-4f * 121.f * 121.f;
    const float C2n = 9e-4f * 121.f * 121.f;
    float m1 = s0 * s1;
    float q1 = fmaf(s0, s0, s1 * s1);
    float A1 = fmaf(2.f, m1, C1n);
    float B1 = q1 + C1n;
    float A2 = fmaf(2.f * cn, fmaf(NP, sx, -m1), C2n);
    float B2 = fmaf(cn, fmaf(NP, sq, -q1), C2n);
    return A1 * A2 * __builtin_amdgcn_rcpf(B1 * B2);
}

__global__ __launch_bounds__(256)
void ssim_main(const float* __restrict__ Pg, const float* __restrict__ Tg,
               float* __restrict__ outp) {
    const int tid  = threadIdx.x;
    const int lane = tid & 63;
    const int wv   = tid >> 6;
    const int Wid  = blockIdx.x * 4 + wv;      // 0..1919
    const int img   = Wid / 60;                // 5 strips * 12 bands
    const int rem   = Wid - img * 60;
    const int strip = rem / NBANDS;
    const int band  = rem - strip * NBANDS;

    const int col0 = (strip == 4) ? 472 : strip * 118;
    const int outw = (strip == 4) ? 30 : 118;
    const int y0   = band * BANDR;
    const int rows = min(BANDR, OH - y0);      // band 11: 18

    const int cload = min(col0 + 2 * lane, 510);
    const bool ok   = lane < (outw >> 1);

    const float* Pb = Pg + img * (WW * WW);
    const float* Tb = Tg + img * (WW * WW);

    float2 prr[11], trr[11];
    float sp0 = 0.f, sp1 = 0.f, st0 = 0.f, st1 = 0.f;
    float sq0 = 0.f, sq1 = 0.f, sx0 = 0.f, sx1 = 0.f;

    // ---- prime: input rows y0..y0+9 into ring slots 0..9 ----
    #pragma unroll
    for (int r = 0; r < 10; ++r) {
        float2 p = *(const float2*)(Pb + (y0 + r) * WW + cload);
        float2 t = *(const float2*)(Tb + (y0 + r) * WW + cload);
        prr[r] = p; trr[r] = t;
        sp0 += p.x; sp1 += p.y; st0 += t.x; st1 += t.y;
        sq0 = fmaf(p.x, p.x, sq0); sq0 = fmaf(t.x, t.x, sq0);
        sq1 = fmaf(p.y, p.y, sq1); sq1 = fmaf(t.y, t.y, sq1);
        sx0 = fmaf(p.x, t.x, sx0); sx1 = fmaf(p.y, t.y, sx1);
    }
    float2 Pn = *(const float2*)(Pb + (y0 + 10) * WW + cload);
    float2 Tn = *(const float2*)(Tb + (y0 + 10) * WW + cload);

    float acc = 0.f;

    for (int yy = 0; yy < rows; yy += 11) {
        #pragma unroll
        for (int j = 0; j < 11; ++j) {
            if (yy + j < rows) {               // wave-uniform guard
                const int sn = (10 + j) % 11;  // static after unroll
                // consume prefetched new row
                float2 Pc = Pn, Tc = Tn;
                prr[sn] = Pc; trr[sn] = Tc;
                sp0 += Pc.x; sp1 += Pc.y; st0 += Tc.x; st1 += Tc.y;
                sq0 = fmaf(Pc.x, Pc.x, sq0); sq0 = fmaf(Tc.x, Tc.x, sq0);
                sq1 = fmaf(Pc.y, Pc.y, sq1); sq1 = fmaf(Tc.y, Tc.y, sq1);
                sx0 = fmaf(Pc.x, Tc.x, sx0); sx1 = fmaf(Pc.y, Tc.y, sx1);
                // prefetch next row (clamped: always in-bounds)
                int nr = min(y0 + 11 + yy + j, 511);
                Pn = *(const float2*)(Pb + nr * WW + cload);
                Tn = *(const float2*)(Tb + nr * WW + cload);
                // horizontal windows + SSIM (pure DPP, no LDS traffic)
                float2 w0 = hwin(sp0, sp1);
                float2 w1 = hwin(st0, st1);
                float2 w2 = hwin(sq0, sq1);
                float2 w3 = hwin(sx0, sx1);
                if (ok) {
                    acc += ssim_term(w0.x, w1.x, w2.x, w3.x);
                    acc += ssim_term(w0.y, w1.y, w2.y, w3.y);
                }
                // subtract oldest row (ring slot j)
                float2 po = prr[j], to = trr[j];
                sp0 -= po.x; sp1 -= po.y; st0 -= to.x; st1 -= to.y;
                sq0 = fmaf(po.x, -po.x, sq0); sq0 = fmaf(to.x, -to.x, sq0);
                sq1 = fmaf(po.y, -po.y, sq1); sq1 = fmaf(to.y, -to.y, sq1);
                sx0 = fmaf(po.x, -to.x, sx0); sx1 = fmaf(po.y, -to.y, sx1);
            }
        }
    }

    // ---- reduce: wave -> block -> one atomicAdd ----
    #pragma unroll
    for (int off = 32; off > 0; off >>= 1) acc += __shfl_down(acc, off);
    __shared__ float wred[4];
    if (lane == 0) wred[wv] = acc;
    __syncthreads();
    if (tid == 0) {
        float s = wred[0] + wred[1] + wred[2] + wred[3];
        float contrib = -s * INV_N;
        if (blockIdx.x == 0) contrib += 1.0f;
        atomicAdd(outp, contrib);
    }
}

extern "C" void kernel_launch(void* const* d_in, const int* in_sizes, int n_in,
                              void* d_out, int out_size, void* d_ws, size_t ws_size,
                              hipStream_t stream) {
    const float* pred = (const float*)d_in[0];
    const float* targ = (const float*)d_in[1];
    float* out = (float*)d_out;

    hipMemsetAsync(out, 0, sizeof(float), stream);
    ssim_main<<<dim3(480), dim3(256), 0, stream>>>(pred, targ, out);
}

// Round 9
// 107.732 us; speedup vs baseline: 1.0576x; 1.0090x over previous
//
#include <hip/hip_runtime.h>

// SSIM loss, wave-autonomous + register ring buffer. B=32, H=W=512, win=11.
// Each wave: 128-col strip (118 outputs, 2 cols/lane) x 44-row band.
// Vertical moment sums in registers; trailing 11 rows ring-buffered in VGPRs.
// Horizontal 11-tap via DPP-only wave_shl:1 chains.
// ROUND 9: NO data-dependent guard in the hot loop -- every band runs exactly
// 44 straight-line rows (band 11: 26 gated-out garbage rows off clamped
// row-511 loads), so the depth-3 prefetch pipeline renames cleanly instead of
// forcing early vmcnt waits under a branch (the r5/r6/r7 regression cause).
// 1920 waves = 480 blocks x 256 thr. atomicAdd into d_out.

#define WW 512
#define OH 502
#define BANDR 44
#define NBANDS 12
#define INV_N (1.0f / 8064128.0f)   // 32*502*502

// lane l receives lane l+1's value; bound_ctrl=1 (OOB -> 0).
__device__ __forceinline__ float shl1(float x) {
    return __int_as_float(__builtin_amdgcn_update_dpp(
        0, __float_as_int(x), 0x130, 0xf, 0xf, true));
}

// 11-tap horizontal window sums for this lane's two columns (2l, 2l+1).
// A = pairs l..l+5 (cols 2l..2l+11, 12 taps); u = col 2l+11.
// W0 = A - u = cols 2l..2l+10; W1 = A - v0 = cols 2l+1..2l+11.
__device__ __forceinline__ float2 hwin(float v0, float v1) {
    float e = v0 + v1;
    float t = shl1(e);  float A = e + t;
    t = shl1(t);  A += t;
    t = shl1(t);  A += t;
    t = shl1(t);  A += t;
    t = shl1(t);  A += t;
    float u = shl1(v1);
    u = shl1(u); u = shl1(u); u = shl1(u); u = shl1(u);  // v1[l+5] = col 2l+11
    return make_float2(A - u, A - v0);
}

__device__ __forceinline__ float ssim_term(float s0, float s1, float sq, float sx) {
    const float NP  = 121.f;
    const float cn  = 121.f / 120.f;
    const float C1n = 1e-4f * 121.f * 121.f;
    const float C2n = 9e-4f * 121.f * 121.f;
    float m1 = s0 * s1;
    float q1 = fmaf(s0, s0, s1 * s1);
    float A1 = fmaf(2.f, m1, C1n);
    float B1 = q1 + C1n;
    float A2 = fmaf(2.f * cn, fmaf(NP, sx, -m1), C2n);
    float B2 = fmaf(cn, fmaf(NP, sq, -q1), C2n);
    return A1 * A2 * __builtin_amdgcn_rcpf(B1 * B2);
}

__global__ __launch_bounds__(256)
void ssim_main(const float* __restrict__ Pg, const float* __restrict__ Tg,
               float* __restrict__ outp) {
    const int tid  = threadIdx.x;
    const int lane = tid & 63;
    const int wv   = tid >> 6;
    const int Wid  = blockIdx.x * 4 + wv;      // 0..1919
    const int img   = Wid / 60;                // 5 strips * 12 bands
    const int rem   = Wid - img * 60;
    const int strip = rem / NBANDS;
    const int band  = rem - strip * NBANDS;

    const int col0 = (strip == 4) ? 472 : strip * 118;
    const int outw = (strip == 4) ? 30 : 118;
    const int y0   = band * BANDR;

    const int cload = min(col0 + 2 * lane, 510);
    const bool ok   = lane < (outw >> 1);

    const float* Pb = Pg + img * (WW * WW);
    const float* Tb = Tg + img * (WW * WW);

    float2 prr[11], trr[11];
    float sp0 = 0.f, sp1 = 0.f, st0 = 0.f, st1 = 0.f;
    float sq0 = 0.f, sq1 = 0.f, sx0 = 0.f, sx1 = 0.f;

    // ---- prime: input rows y0..y0+9 into ring slots 0..9 ----
    #pragma unroll
    for (int r = 0; r < 10; ++r) {
        float2 p = *(const float2*)(Pb + (y0 + r) * WW + cload);
        float2 t = *(const float2*)(Tb + (y0 + r) * WW + cload);
        prr[r] = p; trr[r] = t;
        sp0 += p.x; sp1 += p.y; st0 += t.x; st1 += t.y;
        sq0 = fmaf(p.x, p.x, sq0); sq0 = fmaf(t.x, t.x, sq0);
        sq1 = fmaf(p.y, p.y, sq1); sq1 = fmaf(t.y, t.y, sq1);
        sx0 = fmaf(p.x, t.x, sx0); sx1 = fmaf(p.y, t.y, sx1);
    }
    // depth-3 prefetch pipeline: rows y0+10 .. y0+12 (always valid addresses)
    float2 Pn0 = *(const float2*)(Pb + (y0 + 10) * WW + cload);
    float2 Tn0 = *(const float2*)(Tb + (y0 + 10) * WW + cload);
    float2 Pn1 = *(const float2*)(Pb + (y0 + 11) * WW + cload);
    float2 Tn1 = *(const float2*)(Tb + (y0 + 11) * WW + cload);
    float2 Pn2 = *(const float2*)(Pb + min(y0 + 12, 511) * WW + cload);
    float2 Tn2 = *(const float2*)(Tb + min(y0 + 12, 511) * WW + cload);

    float acc = 0.f;

    for (int blk = 0; blk < 4; ++blk) {          // 4 x 11 = 44 rows, no guards
        #pragma unroll
        for (int j = 0; j < 11; ++j) {
            const int sn = (10 + j) % 11;        // static ring slot
            const int y  = y0 + 11 * blk + j;    // output row this iter makes
            // consume prefetched row (loaded 3 iterations ago)
            float2 Pc = Pn0, Tc = Tn0;
            // rotate pipeline (renamed by compiler: straight-line code)
            Pn0 = Pn1; Tn0 = Tn1;
            Pn1 = Pn2; Tn1 = Tn2;
            int nr = min(y + 13, 511);
            Pn2 = *(const float2*)(Pb + nr * WW + cload);
            Tn2 = *(const float2*)(Tb + nr * WW + cload);
            // vertical: add new row
            prr[sn] = Pc; trr[sn] = Tc;
            sp0 += Pc.x; sp1 += Pc.y; st0 += Tc.x; st1 += Tc.y;
            sq0 = fmaf(Pc.x, Pc.x, sq0); sq0 = fmaf(Tc.x, Tc.x, sq0);
            sq1 = fmaf(Pc.y, Pc.y, sq1); sq1 = fmaf(Tc.y, Tc.y, sq1);
            sx0 = fmaf(Pc.x, Tc.x, sx0); sx1 = fmaf(Pc.y, Tc.y, sx1);
            // horizontal windows + SSIM (pure DPP)
            float2 w0 = hwin(sp0, sp1);
            float2 w1 = hwin(st0, st1);
            float2 w2 = hwin(sq0, sq1);
            float2 w3 = hwin(sx0, sx1);
            if (ok && y < OH) {                  // gate accumulate only
                acc += ssim_term(w0.x, w1.x, w2.x, w3.x);
                acc += ssim_term(w0.y, w1.y, w2.y, w3.y);
            }
            // vertical: subtract oldest row (ring slot j)
            float2 po = prr[j], to = trr[j];
            sp0 -= po.x; sp1 -= po.y; st0 -= to.x; st1 -= to.y;
            sq0 = fmaf(po.x, -po.x, sq0); sq0 = fmaf(to.x, -to.x, sq0);
            sq1 = fmaf(po.y, -po.y, sq1); sq1 = fmaf(to.y, -to.y, sq1);
            sx0 = fmaf(po.x, -to.x, sx0); sx1 = fmaf(po.y, -to.y, sx1);
        }
    }

    // ---- reduce: wave -> block -> one atomicAdd ----
    #pragma unroll
    for (int off = 32; off > 0; off >>= 1) acc += __shfl_down(acc, off);
    __shared__ float wred[4];
    if (lane == 0) wred[wv] = acc;
    __syncthreads();
    if (tid == 0) {
        float s = wred[0] + wred[1] + wred[2] + wred[3];
        float contrib = -s * INV_N;
        if (blockIdx.x == 0) contrib += 1.0f;
        atomicAdd(outp, contrib);
    }
}

extern "C" void kernel_launch(void* const* d_in, const int* in_sizes, int n_in,
                              void* d_out, int out_size, void* d_ws, size_t ws_size,
                              hipStream_t stream) {
    const float* pred = (const float*)d_in[0];
    const float* targ = (const float*)d_in[1];
    float* out = (float*)d_out;

    hipMemsetAsync(out, 0, sizeof(float), stream);
    ssim_main<<<dim3(480), dim3(256), 0, stream>>>(pred, targ, out);
}

// Round 10
// 106.021 us; speedup vs baseline: 1.0747x; 1.0161x over previous
//
#include <hip/hip_runtime.h>

// SSIM loss, wave-autonomous + register ring buffer. B=32, H=W=512, win=11.
// Each wave: 128-col strip (118 outputs, 2 cols/lane) x 22-row band.
// R10: 23 bands x 22 rows -> 3680 waves (3.6/SIMD, ~2x R9) to attack the
// latency-bound 25% VALUBusy; guard-free straight-line body retained from R9
// (22 = 2x11 keeps ring slots compile-time static). Band halo refetch is
// L3-resident (inputs 64 MB << 256 MB L3) so HBM FETCH stays ~flat.
// Vertical moments in registers; trailing 11 rows ring-buffered in VGPRs.
// Horizontal 11-tap via DPP-only wave_shl:1 chains. atomicAdd into d_out.

#define WW 512
#define OH 502
#define BANDR 22
#define NBANDS 23
#define INV_N (1.0f / 8064128.0f)   // 32*502*502

// lane l receives lane l+1's value; bound_ctrl=1 (OOB -> 0).
__device__ __forceinline__ float shl1(float x) {
    return __int_as_float(__builtin_amdgcn_update_dpp(
        0, __float_as_int(x), 0x130, 0xf, 0xf, true));
}

// 11-tap horizontal window sums for this lane's two columns (2l, 2l+1).
// A = pairs l..l+5 (cols 2l..2l+11, 12 taps); u = col 2l+11.
// W0 = A - u = cols 2l..2l+10; W1 = A - v0 = cols 2l+1..2l+11.
__device__ __forceinline__ float2 hwin(float v0, float v1) {
    float e = v0 + v1;
    float t = shl1(e);  float A = e + t;
    t = shl1(t);  A += t;
    t = shl1(t);  A += t;
    t = shl1(t);  A += t;
    t = shl1(t);  A += t;
    float u = shl1(v1);
    u = shl1(u); u = shl1(u); u = shl1(u); u = shl1(u);  // v1[l+5] = col 2l+11
    return make_float2(A - u, A - v0);
}

__device__ __forceinline__ float ssim_term(float s0, float s1, float sq, float sx) {
    const float NP  = 121.f;
    const float cn  = 121.f / 120.f;
    const float C1n = 1e-4f * 121.f * 121.f;
    const float C2n = 9e-4f * 121.f * 121.f;
    float m1 = s0 * s1;
    float q1 = fmaf(s0, s0, s1 * s1);
    float A1 = fmaf(2.f, m1, C1n);
    float B1 = q1 + C1n;
    float A2 = fmaf(2.f * cn, fmaf(NP, sx, -m1), C2n);
    float B2 = fmaf(cn, fmaf(NP, sq, -q1), C2n);
    return A1 * A2 * __builtin_amdgcn_rcpf(B1 * B2);
}

__global__ __launch_bounds__(256)
void ssim_main(const float* __restrict__ Pg, const float* __restrict__ Tg,
               float* __restrict__ outp) {
    const int tid  = threadIdx.x;
    const int lane = tid & 63;
    const int wv   = tid >> 6;
    const int Wid  = blockIdx.x * 4 + wv;      // 0..3679
    const int img   = Wid / 115;               // 5 strips * 23 bands
    const int rem   = Wid - img * 115;
    const int strip = rem / NBANDS;
    const int band  = rem - strip * NBANDS;

    const int col0 = (strip == 4) ? 472 : strip * 118;
    const int outw = (strip == 4) ? 30 : 118;
    const int y0   = band * BANDR;             // band 22: 484 (18 real rows)

    const int cload = min(col0 + 2 * lane, 510);
    const bool ok   = lane < (outw >> 1);

    const float* Pb = Pg + img * (WW * WW);
    const float* Tb = Tg + img * (WW * WW);

    float2 prr[11], trr[11];
    float sp0 = 0.f, sp1 = 0.f, st0 = 0.f, st1 = 0.f;
    float sq0 = 0.f, sq1 = 0.f, sx0 = 0.f, sx1 = 0.f;

    // ---- prime: input rows y0..y0+9 into ring slots 0..9 ----
    #pragma unroll
    for (int r = 0; r < 10; ++r) {
        float2 p = *(const float2*)(Pb + (y0 + r) * WW + cload);
        float2 t = *(const float2*)(Tb + (y0 + r) * WW + cload);
        prr[r] = p; trr[r] = t;
        sp0 += p.x; sp1 += p.y; st0 += t.x; st1 += t.y;
        sq0 = fmaf(p.x, p.x, sq0); sq0 = fmaf(t.x, t.x, sq0);
        sq1 = fmaf(p.y, p.y, sq1); sq1 = fmaf(t.y, t.y, sq1);
        sx0 = fmaf(p.x, t.x, sx0); sx1 = fmaf(p.y, t.y, sx1);
    }
    // depth-3 prefetch pipeline: rows y0+10 .. y0+12 (always valid addresses)
    float2 Pn0 = *(const float2*)(Pb + (y0 + 10) * WW + cload);
    float2 Tn0 = *(const float2*)(Tb + (y0 + 10) * WW + cload);
    float2 Pn1 = *(const float2*)(Pb + (y0 + 11) * WW + cload);
    float2 Tn1 = *(const float2*)(Tb + (y0 + 11) * WW + cload);
    float2 Pn2 = *(const float2*)(Pb + min(y0 + 12, 511) * WW + cload);
    float2 Tn2 = *(const float2*)(Tb + min(y0 + 12, 511) * WW + cload);

    float acc = 0.f;

    for (int blk = 0; blk < 2; ++blk) {          // 2 x 11 = 22 rows, no guards
        #pragma unroll
        for (int j = 0; j < 11; ++j) {
            const int sn = (10 + j) % 11;        // static ring slot
            const int y  = y0 + 11 * blk + j;    // output row this iter makes
            // consume prefetched row (loaded 3 iterations ago)
            float2 Pc = Pn0, Tc = Tn0;
            // rotate pipeline (straight-line: renamed, no real moves)
            Pn0 = Pn1; Tn0 = Tn1;
            Pn1 = Pn2; Tn1 = Tn2;
            int nr = min(y + 13, 511);
            Pn2 = *(const float2*)(Pb + nr * WW + cload);
            Tn2 = *(const float2*)(Tb + nr * WW + cload);
            // vertical: add new row
            prr[sn] = Pc; trr[sn] = Tc;
            sp0 += Pc.x; sp1 += Pc.y; st0 += Tc.x; st1 += Tc.y;
            sq0 = fmaf(Pc.x, Pc.x, sq0); sq0 = fmaf(Tc.x, Tc.x, sq0);
            sq1 = fmaf(Pc.y, Pc.y, sq1); sq1 = fmaf(Tc.y, Tc.y, sq1);
            sx0 = fmaf(Pc.x, Tc.x, sx0); sx1 = fmaf(Pc.y, Tc.y, sx1);
            // horizontal windows + SSIM (pure DPP)
            float2 w0 = hwin(sp0, sp1);
            float2 w1 = hwin(st0, st1);
            float2 w2 = hwin(sq0, sq1);
            float2 w3 = hwin(sx0, sx1);
            if (ok && y < OH) {                  // gate accumulate only
                acc += ssim_term(w0.x, w1.x, w2.x, w3.x);
                acc += ssim_term(w0.y, w1.y, w2.y, w3.y);
            }
            // vertical: subtract oldest row (ring slot j)
            float2 po = prr[j], to = trr[j];
            sp0 -= po.x; sp1 -= po.y; st0 -= to.x; st1 -= to.y;
            sq0 = fmaf(po.x, -po.x, sq0); sq0 = fmaf(to.x, -to.x, sq0);
            sq1 = fmaf(po.y, -po.y, sq1); sq1 = fmaf(to.y, -to.y, sq1);
            sx0 = fmaf(po.x, -to.x, sx0); sx1 = fmaf(po.y, -to.y, sx1);
        }
    }

    // ---- reduce: wave -> block -> one atomicAdd ----
    #pragma unroll
    for (int off = 32; off > 0; off >>= 1) acc += __shfl_down(acc, off);
    __shared__ float wred[4];
    if (lane == 0) wred[wv] = acc;
    __syncthreads();
    if (tid == 0) {
        float s = wred[0] + wred[1] + wred[2] + wred[3];
        float contrib = -s * INV_N;
        if (blockIdx.x == 0) contrib += 1.0f;
        atomicAdd(outp, contrib);
    }
}

extern "C" void kernel_launch(void* const* d_in, const int* in_sizes, int n_in,
                              void* d_out, int out_size, void* d_ws, size_t ws_size,
                              hipStream_t stream) {
    const float* pred = (const float*)d_in[0];
    const float* targ = (const float*)d_in[1];
    float* out = (float*)d_out;

    hipMemsetAsync(out, 0, sizeof(float), stream);
    ssim_main<<<dim3(920), dim3(256), 0, stream>>>(pred, targ, out);
}